// Round 7
// baseline (61.537 us; speedup 1.0000x reference)
//
#include <hip/hip_runtime.h>
#include <hip/hip_bf16.h>
#include <math.h>

typedef _Float16 half8  __attribute__((ext_vector_type(8)));
typedef _Float16 half4v __attribute__((ext_vector_type(4)));
typedef __fp16   fp16x2 __attribute__((ext_vector_type(2)));
typedef float    f32x4  __attribute__((ext_vector_type(4)));
typedef float    f32x16 __attribute__((ext_vector_type(16)));
typedef int      i32x2v __attribute__((ext_vector_type(2)));

#define DDIM 128
#define LQ   512
#define NKV  2048
#define KVB  64
#define NIT  8     // chunks per quarter: 4 quarters x 8 x 64 = 2048

union U32H2 { unsigned u; fp16x2 h; };
union PW    { unsigned u[4]; half8 h; };

// permlane32_swap(a,b) -> ([a_lo|b_lo], [a_hi|b_hi])  (ISA: V_PERMLANE32_SWAP_B32)
__device__ __forceinline__ float xmax64(float v) {
  i32x2v r = __builtin_amdgcn_permlane32_swap(__float_as_int(v), __float_as_int(v), false, false);
  return fmaxf(__int_as_float(r[0]), __int_as_float(r[1]));
}
__device__ __forceinline__ float xsum64(float v) {
  i32x2v r = __builtin_amdgcn_permlane32_swap(__float_as_int(v), __float_as_int(v), false, false);
  return __int_as_float(r[0]) + __int_as_float(r[1]);
}

__global__ __launch_bounds__(512, 2)
void gattn(const float* __restrict__ seq, const float* __restrict__ fism,
           float* __restrict__ out)
{
  const int tid  = threadIdx.x;
  const int lane = tid & 63;
  const int wv   = tid >> 6;      // 0..7
  const int wq   = wv & 1;        // q-group: 32 rows
  const int kvq  = wv >> 1;       // KV quarter 0..3
  const int l31  = lane & 31;
  const int hi   = lane >> 5;

  const int swz = (blockIdx.x & 7) * 32 + (blockIdx.x >> 3);
  const int b   = swz >> 3;
  const int qb  = (swz & 7) * 64;

  const float* seqB = seq  + (size_t)b * LQ * DDIM;
  const float* fisB = fism + (size_t)b * NKV * DDIM;
  float*       outB = out  + (size_t)b * LQ * DDIM;

  __shared__ _Float16 Ksh[4][KVB * DDIM];      // [64][128] f16, 4-bit row-XOR swizzle
  __shared__ _Float16 VTsh[4][(DDIM/2) * 128]; // V^T packed: [d>>1][(d&1)*64 + kv], XOR-swizzled
  __shared__ float    stats[4][2][32][3];

  // ---- Q fragments: B-frag of QK (col=q=l31, k=8hi+j per 16-block c) ----
  half8 qf[8];
  {
    const int qrow = qb + wq * 32 + l31;
    #pragma unroll
    for (int c = 0; c < 8; ++c) {
      const float* p = seqB + (size_t)qrow * DDIM + c * 16 + hi * 8;
      float4 a  = *(const float4*)p;
      float4 b2 = *(const float4*)(p + 4);
      half8 h;
      h[0]=(_Float16)a.x;  h[1]=(_Float16)a.y;  h[2]=(_Float16)a.z;  h[3]=(_Float16)a.w;
      h[4]=(_Float16)b2.x; h[5]=(_Float16)b2.y; h[6]=(_Float16)b2.z; h[7]=(_Float16)b2.w;
      qf[c] = h;
    }
  }

  const int sp   = tid >> 3;     // 0..63
  const int dgrp = tid & 7;
  const int qstg = sp >> 4;      // staging quarter
  const int spc  = sp & 15;      // rows {4spc..4spc+3}

  f32x16 acc[4];
  #pragma unroll
  for (int dt = 0; dt < 4; ++dt)
    #pragma unroll
    for (int i = 0; i < 16; ++i) acc[dt][i] = 0.f;

  float m_run = -INFINITY, tmax = -INFINITY, S_run = 0.f;

  auto write_stage = [&](const float4* v) {
    #pragma unroll
    for (int r = 0; r < 4; ++r) {
      const int row = 4*spc + r;
      #pragma unroll
      for (int hh = 0; hh < 2; ++hh) {
        const float4 x = v[r*4 + hh*2];
        const float4 y = v[r*4 + hh*2 + 1];
        half8 h;
        h[0]=(_Float16)x.x; h[1]=(_Float16)x.y; h[2]=(_Float16)x.z; h[3]=(_Float16)x.w;
        h[4]=(_Float16)y.x; h[5]=(_Float16)y.y; h[6]=(_Float16)y.z; h[7]=(_Float16)y.w;
        const int idx = row*DDIM + ((dgrp*16 + hh*8) ^ (8*(row & 15)));
        *(half8*)&Ksh[qstg][idx] = h;
      }
    }
    #pragma unroll
    for (int k = 0; k < 16; ++k) {
      const int d = dgrp*16 + k;
      const int dRow = d >> 1, dSub = d & 1;
      half4v pk;
      #pragma unroll
      for (int r = 0; r < 4; ++r)
        pk[r] = (_Float16)(((const float*)&v[r*4 + (k>>2)])[k&3]);
      const int idx = dRow*128 + ((dSub*64 + 4*spc) ^ (8*(dRow & 15)));
      *(half4v*)&VTsh[qstg][idx] = pk;
    }
  };

  auto load_glb = [&](float4* v, int t) {
    const float* src = fisB + (size_t)(qstg*(NKV/4) + t*KVB) * DDIM;
    #pragma unroll
    for (int r = 0; r < 4; ++r)
      #pragma unroll
      for (int k = 0; k < 4; ++k)
        v[r*4+k] = *(const float4*)(src + (size_t)(4*spc + r)*DDIM + dgrp*16 + k*4);
  };

  { // prologue
    float4 stg[16];
    load_glb(stg, 0);
    write_stage(stg);
  }

  for (int t = 0; t < NIT; ++t) {
    __syncthreads();                 // A: iter-t buffers ready
    float4 nxt[16];
    const bool have = (t + 1 < NIT);
    if (have) load_glb(nxt, t + 1);

    // ---- QK^T: A=K (m=kv), B=Q (col=q). sv[ns]: col=q=l31, row=kv32 ----
    f32x16 sv[2];
    #pragma unroll
    for (int ns = 0; ns < 2; ++ns) {
      f32x16 x;
      #pragma unroll
      for (int i = 0; i < 16; ++i) x[i] = 0.f;
      const int row = ns*32 + l31;
      const int sw  = 8*(row & 15);
      #pragma unroll
      for (int c = 0; c < 8; ++c) {
        const int idx = row*DDIM + ((c*16 + hi*8) ^ sw);
        half8 kf = *(const half8*)&Ksh[kvq][idx];
        x = __builtin_amdgcn_mfma_f32_32x32x16_f16(kf, qf[c], x, 0, 0, 0);
      }
      sv[ns] = x;
    }

    // ---- online power-softmax: lane-local trees + 1 permlane exchange ----
    float mx[16];
    #pragma unroll
    for (int i = 0; i < 16; ++i) mx[i] = fmaxf(sv[0][i], sv[1][i]);
    #pragma unroll
    for (int st = 8; st > 0; st >>= 1)
      #pragma unroll
      for (int i = 0; i < st; ++i) mx[i] = fmaxf(mx[i], mx[i+st]);
    const float cmax = xmax64(mx[0]);
    tmax = fmaxf(tmax, cmax);
    if (__any(cmax > m_run + 8.f)) {
      const float mn = fmaxf(m_run, cmax);
      const float sc = __expf(m_run - mn);
      S_run *= sc;
      m_run = mn;
      #pragma unroll
      for (int dt = 0; dt < 4; ++dt) acc[dt] *= sc;   // per-lane scalar (col=q)
    }
    float ts[16];
    #pragma unroll
    for (int i = 0; i < 16; ++i) {
      const float p0 = __expf(sv[0][i] - m_run);
      const float p1 = __expf(sv[1][i] - m_run);
      sv[0][i] = p0; sv[1][i] = p1;
      ts[i] = p0 + p1;
    }
    #pragma unroll
    for (int st = 8; st > 0; st >>= 1)
      #pragma unroll
      for (int i = 0; i < st; ++i) ts[i] += ts[i+st];
    S_run += xsum64(ts[0]);

    // ---- P pack + permlane redistribute (T12) ----
    // sv[ns][8b0+r']: kv_off (r'&3)+8*(r'>>2)+4hi within 16-block (ns,b0).
    // B-frag word w needs kv_off = 8hi + 2w + {0,1}:
    //   word0=[pk01_lo|pk45_lo]=swap(t0,t2)[0], word2=[pk01_hi|pk45_hi]=swap(t0,t2)[1]
    //   word1=swap(t1,t3)[0],                   word3=swap(t1,t3)[1]
    PW pw[4];
    #pragma unroll
    for (int ns = 0; ns < 2; ++ns)
      #pragma unroll
      for (int b0 = 0; b0 < 2; ++b0) {
        U32H2 t0, t1, t2, t3;
        t0.h = __builtin_amdgcn_cvt_pkrtz(sv[ns][8*b0+0], sv[ns][8*b0+1]);
        t1.h = __builtin_amdgcn_cvt_pkrtz(sv[ns][8*b0+2], sv[ns][8*b0+3]);
        t2.h = __builtin_amdgcn_cvt_pkrtz(sv[ns][8*b0+4], sv[ns][8*b0+5]);
        t3.h = __builtin_amdgcn_cvt_pkrtz(sv[ns][8*b0+6], sv[ns][8*b0+7]);
        i32x2v r0 = __builtin_amdgcn_permlane32_swap((int)t0.u, (int)t2.u, false, false);
        i32x2v r1 = __builtin_amdgcn_permlane32_swap((int)t1.u, (int)t3.u, false, false);
        const int kb = 2*ns + b0;
        pw[kb].u[0] = (unsigned)r0[0];
        pw[kb].u[1] = (unsigned)r1[0];
        pw[kb].u[2] = (unsigned)r0[1];
        pw[kb].u[3] = (unsigned)r1[1];
      }

    // ---- PV (transposed): A=V^T (m=d), B=P (col=q). acc[dt]: row=d, col=q ----
    #pragma unroll
    for (int dt = 0; dt < 4; ++dt) {
      const int d    = dt*32 + l31;
      const int dRow = d >> 1, dSub = d & 1;
      const int sw   = 8*(dRow & 15);
      #pragma unroll
      for (int kb = 0; kb < 4; ++kb) {
        const int idx = dRow*128 + ((dSub*64 + kb*16 + hi*8) ^ sw);
        half8 vtf = *(const half8*)&VTsh[kvq][idx];
        acc[dt] = __builtin_amdgcn_mfma_f32_32x32x16_f16(vtf, pw[kb].h, acc[dt], 0, 0, 0);
      }
    }

    __syncthreads();                 // B: done reading iter t
    if (have) write_stage(nxt);
  }

  __syncthreads();

  // ---- 4-way combine: quarters 1..3 spill acc via LDS ----
  float* Kf  = (float*)&Ksh[0][0];   // 16384 floats: regions 0..3
  float* VTf = (float*)&VTsh[0][0];  // regions 4..5
  if (kvq != 0) {
    const int rgn = (kvq - 1) * 2 + wq;
    float* base = (rgn < 4) ? (Kf + rgn * 4096) : (VTf + (rgn - 4) * 4096);
    #pragma unroll
    for (int dt = 0; dt < 4; ++dt)
      #pragma unroll
      for (int rg = 0; rg < 4; ++rg) {
        f32x4 v = {acc[dt][4*rg+0], acc[dt][4*rg+1], acc[dt][4*rg+2], acc[dt][4*rg+3]};
        *(f32x4*)&base[lane*64 + (((dt*4+rg) ^ (lane & 15)) * 4)] = v;
      }
    if (lane < 32) {
      stats[kvq][wq][lane][0] = m_run;
      stats[kvq][wq][lane][1] = S_run;
      stats[kvq][wq][lane][2] = tmax;
    }
  }
  __syncthreads();

  if (kvq == 0) {
    float mj[4], Sj[4], tj[4];
    mj[0] = m_run; Sj[0] = S_run; tj[0] = tmax;
    #pragma unroll
    for (int j = 1; j < 4; ++j) {
      mj[j] = stats[j][wq][l31][0];
      Sj[j] = stats[j][wq][l31][1];
      tj[j] = stats[j][wq][l31][2];
    }
    const float M = fmaxf(fmaxf(tj[0], tj[1]), fmaxf(tj[2], tj[3]));
    float fj[4], den = 0.f;
    #pragma unroll
    for (int j = 0; j < 4; ++j) { fj[j] = __expf(mj[j] - M); den += fj[j] * Sj[j]; }
    const float rs = rsqrtf(den);
    #pragma unroll
    for (int j = 0; j < 4; ++j) fj[j] *= rs;   // per-lane scalars (col=q)

    const int qrow = qb + wq*32 + l31;
    #pragma unroll
    for (int dt = 0; dt < 4; ++dt) {
      #pragma unroll
      for (int rg = 0; rg < 4; ++rg) {
        f32x4 av = {acc[dt][4*rg+0], acc[dt][4*rg+1], acc[dt][4*rg+2], acc[dt][4*rg+3]};
        av *= fj[0];
        #pragma unroll
        for (int j = 1; j < 4; ++j) {
          const int rgn = (j - 1) * 2 + wq;
          const float* base = (rgn < 4) ? (Kf + rgn * 4096) : (VTf + (rgn - 4) * 4096);
          const f32x4 pj = *(const f32x4*)&base[lane*64 + (((dt*4+rg) ^ (lane & 15)) * 4)];
          av += pj * fj[j];
        }
        const int d0 = dt*32 + rg*8 + hi*4;
        const float4 s = *(const float4*)&seqB[(size_t)qrow * DDIM + d0];
        float4 o;
        o.x = 0.5f * s.x * (1.f + av[0]);
        o.y = 0.5f * s.y * (1.f + av[1]);
        o.z = 0.5f * s.z * (1.f + av[2]);
        o.w = 0.5f * s.w * (1.f + av[3]);
        *(float4*)&outB[(size_t)qrow * DDIM + d0] = o;
      }
    }
  }
}

extern "C" void kernel_launch(void* const* d_in, const int* in_sizes, int n_in,
                              void* d_out, int out_size, void* d_ws, size_t ws_size,
                              hipStream_t stream) {
  const float* seq  = (const float*)d_in[0];
  const float* fism = (const float*)d_in[1];
  float* out = (float*)d_out;
  gattn<<<dim3(256), dim3(512), 0, stream>>>(seq, fism, out);
}